// Round 2
// baseline (590.198 us; speedup 1.0000x reference)
//
#include <hip/hip_runtime.h>

#define D 128
#define DW 64   // bf16-pair dwords per row (128 bf16 values)

__device__ __forceinline__ float blo(unsigned p){ return __uint_as_float(p << 16); }
__device__ __forceinline__ float bhi(unsigned p){ return __uint_as_float(p & 0xffff0000u); }
__device__ __forceinline__ unsigned bpack(float a, float b){
  unsigned x = __float_as_uint(a), y = __float_as_uint(b);
  x += 0x7fffu + ((x >> 16) & 1u);   // RNE
  y += 0x7fffu + ((y >> 16) & 1u);
  return (x >> 16) | (y & 0xffff0000u);
}

// d_out doubles as scratch: row i = 128 dwords.
//   dwords [i*128 ..  i*128+64)  : aggx row i (bf16 pairs)  -- written by k_agg
//   dwords [i*128+64 .. i*128+128): xb   row i (bf16 pairs)  -- written by k_prep
// k_gemm reads aggx for its rows, then overwrites the full row with final floats.

// ---- in-degree count (self-loop added later as +1) ----
__global__ void k_deg(const int* __restrict__ ei, int* __restrict__ cnt, int E){
  int e = blockIdx.x*256 + threadIdx.x;
  if (e < E) atomicAdd(cnt + ei[E + e], 1);
}

// ---- exclusive prefix sum over cnt[N]: 3 kernels ----
__global__ void k_scan1(const int* __restrict__ cnt, int* __restrict__ off,
                        int* __restrict__ bsum, int N){
  __shared__ int sm[256];
  int i = blockIdx.x*256 + threadIdx.x;
  int v = (i < N) ? cnt[i] : 0;
  int acc = v;
  sm[threadIdx.x] = acc;
  __syncthreads();
  for (int s = 1; s < 256; s <<= 1){
    int t = (threadIdx.x >= s) ? sm[threadIdx.x - s] : 0;
    __syncthreads();
    acc += t;
    sm[threadIdx.x] = acc;
    __syncthreads();
  }
  if (i < N) off[i] = acc - v;                 // block-local exclusive
  if (threadIdx.x == 255) bsum[blockIdx.x] = acc;
}

__global__ void k_scan2(int* __restrict__ bsum, int nb){
  __shared__ int sm[512];
  int v = (threadIdx.x < nb) ? bsum[threadIdx.x] : 0;
  int acc = v;
  sm[threadIdx.x] = acc;
  __syncthreads();
  for (int s = 1; s < 512; s <<= 1){
    int t = (threadIdx.x >= s) ? sm[threadIdx.x - s] : 0;
    __syncthreads();
    acc += t;
    sm[threadIdx.x] = acc;
    __syncthreads();
  }
  if (threadIdx.x < nb) bsum[threadIdx.x] = acc - v;  // exclusive block bases
}

__global__ void k_scan3(int* __restrict__ off, const int* __restrict__ bsum,
                        int* __restrict__ cursor, int N){
  int i = blockIdx.x*256 + threadIdx.x;
  if (i < N){
    int o = off[i] + bsum[blockIdx.x];
    off[i] = o;
    cursor[i] = o;
  }
}

// ---- xb[i] = bf16(x[i] * dis[i]), dis = rsqrt(indeg+1); store in out upper half ----
__global__ void k_prep(const float* __restrict__ x, const int* __restrict__ cnt,
                       unsigned* __restrict__ out_u, int N){
  int idx = blockIdx.x*256 + threadIdx.x;
  if (idx >= N*DW) return;
  int row = idx >> 6, col = idx & 63;
  float dis = rsqrtf((float)(cnt[row] + 1));
  float2 xv = reinterpret_cast<const float2*>(x)[idx];
  out_u[(size_t)row*128 + 64 + col] = bpack(xv.x * dis, xv.y * dis);
}

// ---- scatter edge src ids into CSR buckets (keyed by dst) ----
__global__ void k_fill(const int* __restrict__ ei, int* __restrict__ cursor,
                       int* __restrict__ elist, int E){
  int e = blockIdx.x*256 + threadIdx.x;
  if (e < E){
    int d = ei[E + e];
    int pos = atomicAdd(cursor + d, 1);
    elist[pos] = ei[e];
  }
}

// ---- one wave per node: agg[i] = dis[i]*(sum_{src in in(i)} xb[src] + xb[i]) ----
__global__ __launch_bounds__(256) void k_agg(unsigned* __restrict__ out_u,
    const int* __restrict__ elist, const int* __restrict__ off,
    const int* __restrict__ cnt, int N){
  const int lane = threadIdx.x & 63;
  int wid = blockIdx.x*4 + (threadIdx.x >> 6);
  const int nw = gridDim.x*4;
  for (int i = wid; i < N; i += nw){
    int node = __builtin_amdgcn_readfirstlane(i);
    int o = off[node];
    int c = cnt[node];
    float a0 = 0.f, a1 = 0.f;
    for (int j0 = 0; j0 < c; j0 += 64){
      int m = c - j0; if (m > 64) m = 64;
      int sid = (j0 + lane < c) ? elist[o + j0 + lane] : 0;
      for (int jj = 0; jj < m; ++jj){
        int s = __shfl(sid, jj);
        unsigned p = out_u[(size_t)s*128 + 64 + lane];   // 256B coalesced gather
        a0 += blo(p); a1 += bhi(p);
      }
    }
    unsigned ps = out_u[(size_t)node*128 + 64 + lane];   // self-loop term
    a0 += blo(ps); a1 += bhi(ps);
    float dis = rsqrtf((float)(c + 1));
    out_u[(size_t)node*128 + lane] = bpack(a0*dis, a1*dis);
  }
}

// ---- fused GEMM: out = aggx@W + b + relu(x@res_W + res_b); BN partial sums ----
__global__ __launch_bounds__(512) void k_gemm(
    const float* __restrict__ x,
    const float* __restrict__ W, const float* __restrict__ RW,
    const float* __restrict__ bias, const float* __restrict__ rbias,
    float* __restrict__ out, float* __restrict__ colsum, int N)
{
  __shared__ unsigned lds[16384];  // [0..8191]=W (bf16 pairs), [8192..]=res_W
  unsigned* out_u = reinterpret_cast<unsigned*>(out);
  for (int idx = threadIdx.x; idx < 8192; idx += 512){
    float2 w = reinterpret_cast<const float2*>(W)[idx];
    lds[idx] = bpack(w.x, w.y);
    float2 r = reinterpret_cast<const float2*>(RW)[idx];
    lds[8192 + idx] = bpack(r.x, r.y);
  }
  __syncthreads();
  const int lane = threadIdx.x & 63;
  const int wave = __builtin_amdgcn_readfirstlane(threadIdx.x >> 6);
  const int row0 = blockIdx.x * 64 + wave * 8;
  const int c0 = 2*lane, c1 = 2*lane + 1;
  float accA0[8]={0,0,0,0,0,0,0,0}, accA1[8]={0,0,0,0,0,0,0,0};
  float accR0[8]={0,0,0,0,0,0,0,0}, accR1[8]={0,0,0,0,0,0,0,0};
  #pragma unroll 4
  for (int kp = 0; kp < 64; ++kp){
    unsigned w0 = lds[(2*kp)*64 + lane];
    unsigned w1 = lds[(2*kp+1)*64 + lane];
    unsigned r0 = lds[8192 + (2*kp)*64 + lane];
    unsigned r1 = lds[8192 + (2*kp+1)*64 + lane];
    float w00=blo(w0), w01=bhi(w0), w10=blo(w1), w11=bhi(w1);
    float q00=blo(r0), q01=bhi(r0), q10=blo(r1), q11=bhi(r1);
    #pragma unroll
    for (int r = 0; r < 8; ++r){
      int row = row0 + r; row = row < N ? row : N-1;   // clamp; results discarded
      unsigned ap = out_u[(size_t)row*128 + kp];       // aggx (uniform -> broadcast)
      float a0 = blo(ap), a1 = bhi(ap);
      float xv0 = x[row*D + 2*kp], xv1 = x[row*D + 2*kp + 1];
      accA0[r] += a0*w00 + a1*w10;
      accA1[r] += a0*w01 + a1*w11;
      accR0[r] += xv0*q00 + xv1*q10;
      accR1[r] += xv0*q01 + xv1*q11;
    }
  }
  float b0 = bias[c0], b1 = bias[c1], rb0 = rbias[c0], rb1 = rbias[c1];
  float s0=0.f, s1=0.f, q0=0.f, q1=0.f;
  #pragma unroll
  for (int r = 0; r < 8; ++r){
    int row = row0 + r;
    if (row < N){
      float y0 = accA0[r] + b0 + fmaxf(accR0[r] + rb0, 0.f);
      float y1 = accA1[r] + b1 + fmaxf(accR1[r] + rb1, 0.f);
      reinterpret_cast<float2*>(out)[(size_t)row*DW + lane] = make_float2(y0, y1);
      s0 += y0; s1 += y1; q0 += y0*y0; q1 += y1*y1;
    }
  }
  __syncthreads();
  float* red = reinterpret_cast<float*>(lds);
  red[threadIdx.x*4+0]=s0; red[threadIdx.x*4+1]=s1;
  red[threadIdx.x*4+2]=q0; red[threadIdx.x*4+3]=q1;
  __syncthreads();
  if (threadIdx.x < 64){
    float t0=0.f,t1=0.f,u0=0.f,u1=0.f;
    #pragma unroll
    for (int w = 0; w < 8; ++w){
      int base = (w*64 + threadIdx.x)*4;
      t0 += red[base]; t1 += red[base+1]; u0 += red[base+2]; u1 += red[base+3];
    }
    atomicAdd(colsum + 2*threadIdx.x,       t0);
    atomicAdd(colsum + 2*threadIdx.x + 1,   t1);
    atomicAdd(colsum + 128 + 2*threadIdx.x, u0);
    atomicAdd(colsum + 128 + 2*threadIdx.x + 1, u1);
  }
}

// ---- BN finalize: per-column scale/shift ----
__global__ void k_bnfinal(const float* __restrict__ colsum, const float* __restrict__ gamma,
                          const float* __restrict__ beta, float* __restrict__ sc, float fN){
  int c = threadIdx.x;
  float mean = colsum[c] / fN;
  float var  = colsum[128 + c] / fN - mean*mean;
  var = fmaxf(var, 0.f);
  float inv = rsqrtf(var + 1e-5f);
  float s = gamma[c] * inv;
  sc[c] = s;
  sc[128 + c] = beta[c] - mean * s;
}

// ---- in-place normalize ----
__global__ void k_norm(float4* __restrict__ out4, const float4* __restrict__ sc4, int n4){
  int idx = blockIdx.x*256 + threadIdx.x;
  int stride = gridDim.x*256;
  for (int i = idx; i < n4; i += stride){
    int cb = i & 31;
    float4 v = out4[i];
    float4 s = sc4[cb];
    float4 t = sc4[32 + cb];
    v.x = v.x*s.x + t.x; v.y = v.y*s.y + t.y;
    v.z = v.z*s.z + t.z; v.w = v.w*s.w + t.w;
    out4[i] = v;
  }
}

extern "C" void kernel_launch(void* const* d_in, const int* in_sizes, int n_in,
                              void* d_out, int out_size, void* d_ws, size_t ws_size,
                              hipStream_t stream){
  const float* x     = (const float*)d_in[0];
  const int*   ei    = (const int*)d_in[1];      // int64 staged as int32 by harness
  const float* W     = (const float*)d_in[2];
  const float* b     = (const float*)d_in[3];
  const float* RW    = (const float*)d_in[4];
  const float* rb    = (const float*)d_in[5];
  const float* gamma = (const float*)d_in[6];
  const float* beta  = (const float*)d_in[7];
  float* out = (float*)d_out;
  unsigned* out_u = (unsigned*)d_out;
  const int N = in_sizes[0] / D;
  const int E = in_sizes[1] / 2;

  char* ws = (char*)d_ws;
  size_t o = 0;
  auto alloc = [&](size_t bytes)->void*{
    void* p = ws + o;
    o += (bytes + 255) & ~size_t(255);
    return p;
  };
  int*   cnt    = (int*)alloc((size_t)N*4);
  int*   off    = (int*)alloc((size_t)N*4);
  int*   cursor = (int*)alloc((size_t)N*4);
  int*   bsum   = (int*)alloc(512*4);
  float* colsum = (float*)alloc(256*4);   // [0..127]=sum, [128..255]=sumsq
  float* scale  = (float*)alloc(256*4);   // [0..127]=scale, [128..255]=shift
  int*   elist  = (int*)alloc((size_t)E*4);
  // total ~3.7 MB — well within any ws_size

  hipMemsetAsync(cnt, 0, (size_t)N*4, stream);
  hipMemsetAsync(colsum, 0, 256*4, stream);

  int egrid = (E + 255)/256;
  int nb = (N + 255)/256;
  k_deg  <<<egrid, 256, 0, stream>>>(ei, cnt, E);
  k_scan1<<<nb,    256, 0, stream>>>(cnt, off, bsum, N);
  k_scan2<<<1,     512, 0, stream>>>(bsum, nb);
  k_scan3<<<nb,    256, 0, stream>>>(off, bsum, cursor, N);
  k_prep <<<(N*DW + 255)/256, 256, 0, stream>>>(x, cnt, out_u, N);
  k_fill <<<egrid, 256, 0, stream>>>(ei, cursor, elist, E);
  k_agg  <<<4096,  256, 0, stream>>>(out_u, elist, off, cnt, N);
  k_gemm <<<(N + 63)/64, 512, 0, stream>>>(x, W, RW, b, rb, out, colsum, N);
  k_bnfinal<<<1, 128, 0, stream>>>(colsum, gamma, beta, scale, (float)N);
  k_norm <<<2048, 256, 0, stream>>>((float4*)out, (const float4*)scale, N*32);
}

// Round 3
// 301.568 us; speedup vs baseline: 1.9571x; 1.9571x over previous
//
#include <hip/hip_runtime.h>
#include <math.h>

#define D 128
#define DW 64   // bf16-pair dwords per row (128 bf16 values)

typedef __attribute__((ext_vector_type(8))) short bf16x8;
typedef __attribute__((ext_vector_type(4))) float f32x4;
union U4 { uint4 u; bf16x8 f; };

__device__ __forceinline__ float blo(unsigned p){ return __uint_as_float(p << 16); }
__device__ __forceinline__ float bhi(unsigned p){ return __uint_as_float(p & 0xffff0000u); }
__device__ __forceinline__ unsigned bpack(float a, float b){
  unsigned x = __float_as_uint(a), y = __float_as_uint(b);
  x += 0x7fffu + ((x >> 16) & 1u);   // RNE
  y += 0x7fffu + ((y >> 16) & 1u);
  return (x >> 16) | (y & 0xffff0000u);
}

// d_out doubles as scratch: row i = 128 dwords.
//   dwords [i*128 ..  i*128+64)  : aggx row i (bf16 pairs)  -- written by k_agg
//   dwords [i*128+64 .. i*128+128): xb   row i (bf16 pairs)  -- written by k_prep
// k_gemm reads both for its rows, then overwrites the full row with final floats.

// ---- in-degree count (self-loop added later as +1) ----
__global__ void k_deg(const int* __restrict__ ei, int* __restrict__ cnt, int E){
  int e = blockIdx.x*256 + threadIdx.x;
  if (e < E) atomicAdd(cnt + ei[E + e], 1);
}

// ---- exclusive prefix sum over cnt[N]: 3 kernels ----
__global__ void k_scan1(const int* __restrict__ cnt, int* __restrict__ off,
                        int* __restrict__ bsum, int N){
  __shared__ int sm[256];
  int i = blockIdx.x*256 + threadIdx.x;
  int v = (i < N) ? cnt[i] : 0;
  int acc = v;
  sm[threadIdx.x] = acc;
  __syncthreads();
  for (int s = 1; s < 256; s <<= 1){
    int t = (threadIdx.x >= s) ? sm[threadIdx.x - s] : 0;
    __syncthreads();
    acc += t;
    sm[threadIdx.x] = acc;
    __syncthreads();
  }
  if (i < N) off[i] = acc - v;
  if (threadIdx.x == 255) bsum[blockIdx.x] = acc;
}

__global__ void k_scan2(int* __restrict__ bsum, int nb){
  __shared__ int sm[512];
  int v = (threadIdx.x < nb) ? bsum[threadIdx.x] : 0;
  int acc = v;
  sm[threadIdx.x] = acc;
  __syncthreads();
  for (int s = 1; s < 512; s <<= 1){
    int t = (threadIdx.x >= s) ? sm[threadIdx.x - s] : 0;
    __syncthreads();
    acc += t;
    sm[threadIdx.x] = acc;
    __syncthreads();
  }
  if (threadIdx.x < nb) bsum[threadIdx.x] = acc - v;
}

__global__ void k_scan3(int* __restrict__ off, const int* __restrict__ bsum,
                        int* __restrict__ cursor, int N){
  int i = blockIdx.x*256 + threadIdx.x;
  if (i < N){
    int o = off[i] + bsum[blockIdx.x];
    off[i] = o;
    cursor[i] = o;
  }
}

// ---- xb[i] = bf16(x[i] * dis[i]), dis = rsqrt(indeg+1); store in out upper half ----
__global__ void k_prep(const float* __restrict__ x, const int* __restrict__ cnt,
                       unsigned* __restrict__ out_u, int N){
  int idx = blockIdx.x*256 + threadIdx.x;
  if (idx >= N*DW) return;
  int row = idx >> 6, col = idx & 63;
  float dis = rsqrtf((float)(cnt[row] + 1));
  float2 xv = reinterpret_cast<const float2*>(x)[idx];
  out_u[(size_t)row*128 + 64 + col] = bpack(xv.x * dis, xv.y * dis);
}

// ---- W/RW -> bf16, transposed (Wt[c][k]) + XOR-swizzled, into ws ----
__global__ void k_wprep(const float* __restrict__ W, const float* __restrict__ RW,
                        unsigned* __restrict__ dst){
  int idx = blockIdx.x*256 + threadIdx.x;   // 16384 total
  int m = idx >> 13;
  int w = idx & 8191;
  int c = w >> 6, kd = w & 63;
  const float* src = m ? RW : W;
  float a = src[(2*kd)*128 + c];
  float b = src[(2*kd+1)*128 + c];
  dst[(m<<13) + c*64 + (kd ^ ((c & 7) << 2))] = bpack(a, b);
}

// ---- scatter edge src ids into CSR buckets (keyed by dst) ----
__global__ void k_fill(const int* __restrict__ ei, int* __restrict__ cursor,
                       int* __restrict__ elist, int E){
  int e = blockIdx.x*256 + threadIdx.x;
  if (e < E){
    int d = ei[E + e];
    int pos = atomicAdd(cursor + d, 1);
    elist[pos] = ei[e];
  }
}

// ---- one wave per node: agg[i] = dis[i]*(sum_{src in in(i)} xb[src] + xb[i]) ----
__global__ __launch_bounds__(256) void k_agg(unsigned* __restrict__ out_u,
    const int* __restrict__ elist, const int* __restrict__ off,
    const int* __restrict__ cnt, int N){
  const int lane = threadIdx.x & 63;
  int wid = blockIdx.x*4 + (threadIdx.x >> 6);
  const int nw = gridDim.x*4;
  for (int i = wid; i < N; i += nw){
    int node = __builtin_amdgcn_readfirstlane(i);
    int o = off[node];
    int c = cnt[node];
    float a0 = 0.f, a1 = 0.f;
    for (int j0 = 0; j0 < c; j0 += 64){
      int m = c - j0; if (m > 64) m = 64;
      int sid = (j0 + lane < c) ? elist[o + j0 + lane] : 0;
      for (int jj = 0; jj < m; ++jj){
        int s = __shfl(sid, jj);
        unsigned p = out_u[(size_t)s*128 + 64 + lane];   // 256B coalesced gather
        a0 += blo(p); a1 += bhi(p);
      }
    }
    unsigned ps = out_u[(size_t)node*128 + 64 + lane];   // self-loop
    a0 += blo(ps); a1 += bhi(ps);
    float dis = rsqrtf((float)(c + 1));
    out_u[(size_t)node*128 + lane] = bpack(a0*dis, a1*dis);
  }
}

// ---- MFMA GEMM: out = aggx@W + b + relu((xb@RW)*s + rb); BN partial sums ----
__global__ __launch_bounds__(512) void k_gemm(
    const unsigned* __restrict__ wsW,     // 16384 dwords: swizzled Wt | RWt
    const float* __restrict__ bias, const float* __restrict__ rbias,
    const int* __restrict__ cnt,
    float* __restrict__ out, float* __restrict__ colsum, int N)
{
  __shared__ unsigned lds[16384];   // 64KB: [0..8191]=Wt, [8192..]=RWt (swizzled)
  unsigned* out_u = reinterpret_cast<unsigned*>(out);
  for (int i = threadIdx.x; i < 16384; i += 512) lds[i] = wsW[i];
  __syncthreads();

  const int lane = threadIdx.x & 63;
  const int wave = threadIdx.x >> 6;
  const int lo = lane & 15, hi = lane >> 4;
  const int rowbase = (blockIdx.x * 8 + wave) * 16;

  float bcol[8], rbcol[8];
  #pragma unroll
  for (int ct = 0; ct < 8; ++ct){
    bcol[ct]  = bias[ct*16 + lo];
    rbcol[ct] = rbias[ct*16 + lo];
  }

  // A fragments: row = rowbase+lo, k-chunk kk, k-offset hi*8
  int arow = rowbase + lo; if (arow >= N) arow = N - 1;   // clamped rows discarded
  U4 aggF[4], xbF[4];
  #pragma unroll
  for (int kk = 0; kk < 4; ++kk){
    aggF[kk].u = *(const uint4*)&out_u[(size_t)arow*128 + kk*16 + hi*4];
    xbF[kk].u  = *(const uint4*)&out_u[(size_t)arow*128 + 64 + kk*16 + hi*4];
  }

  f32x4 accA[8], accR[8];
  #pragma unroll
  for (int ct = 0; ct < 8; ++ct){
    accA[ct] = (f32x4){0.f,0.f,0.f,0.f};
    accR[ct] = (f32x4){0.f,0.f,0.f,0.f};
  }

  #pragma unroll
  for (int ct = 0; ct < 8; ++ct){
    const int c = ct*16 + lo;
    #pragma unroll
    for (int kk = 0; kk < 4; ++kk){
      int kd = (kk*16 + hi*4) ^ ((c & 7) << 2);
      U4 wf, rf;
      wf.u = *(const uint4*)&lds[c*64 + kd];
      rf.u = *(const uint4*)&lds[8192 + c*64 + kd];
      accA[ct] = __builtin_amdgcn_mfma_f32_16x16x32_bf16(aggF[kk].f, wf.f, accA[ct], 0,0,0);
      accR[ct] = __builtin_amdgcn_mfma_f32_16x16x32_bf16(xbF[kk].f, rf.f, accR[ct], 0,0,0);
    }
  }

  // epilogue: C/D layout col=lane&15, row=hi*4+reg
  float s_[4];
  #pragma unroll
  for (int j = 0; j < 4; ++j){
    int r = rowbase + hi*4 + j;
    int rc = r < N ? r : N - 1;
    s_[j] = sqrtf((float)(cnt[rc] + 1));   // undo dis scaling on residual
  }
  float cs[8], cq[8];
  #pragma unroll
  for (int ct = 0; ct < 8; ++ct){ cs[ct] = 0.f; cq[ct] = 0.f; }

  #pragma unroll
  for (int ct = 0; ct < 8; ++ct){
    const int col = ct*16 + lo;
    #pragma unroll
    for (int j = 0; j < 4; ++j){
      int r = rowbase + hi*4 + j;
      if (r < N){
        float y = accA[ct][j] + bcol[ct] + fmaxf(accR[ct][j]*s_[j] + rbcol[ct], 0.f);
        out[(size_t)r*128 + col] = y;
        cs[ct] += y; cq[ct] += y*y;
      }
    }
  }

  // BN partials: reduce 4 row-groups (lanes differing in bits 4-5)
  #pragma unroll
  for (int ct = 0; ct < 8; ++ct){
    cs[ct] += __shfl_xor(cs[ct], 16); cs[ct] += __shfl_xor(cs[ct], 32);
    cq[ct] += __shfl_xor(cq[ct], 16); cq[ct] += __shfl_xor(cq[ct], 32);
  }
  __syncthreads();                 // Wt no longer needed; reuse LDS
  float* red = reinterpret_cast<float*>(lds);
  if (lane < 16){
    #pragma unroll
    for (int ct = 0; ct < 8; ++ct){
      int col = ct*16 + lane;
      red[wave*256 + 2*col]     = cs[ct];
      red[wave*256 + 2*col + 1] = cq[ct];
    }
  }
  __syncthreads();
  if (threadIdx.x < 256){
    float t = 0.f;
    #pragma unroll
    for (int w = 0; w < 8; ++w) t += red[w*256 + threadIdx.x];
    atomicAdd(colsum + threadIdx.x, t);
  }
}

// ---- BN finalize: per-column scale/shift (colsum interleaved sum/sumsq) ----
__global__ void k_bnfinal(const float* __restrict__ colsum, const float* __restrict__ gamma,
                          const float* __restrict__ beta, float* __restrict__ sc, float fN){
  int c = threadIdx.x;
  float mean = colsum[2*c] / fN;
  float var  = colsum[2*c + 1] / fN - mean*mean;
  var = fmaxf(var, 0.f);
  float inv = rsqrtf(var + 1e-5f);
  float s = gamma[c] * inv;
  sc[c] = s;
  sc[128 + c] = beta[c] - mean * s;
}

// ---- in-place normalize ----
__global__ void k_norm(float4* __restrict__ out4, const float4* __restrict__ sc4, int n4){
  int idx = blockIdx.x*256 + threadIdx.x;
  int stride = gridDim.x*256;
  for (int i = idx; i < n4; i += stride){
    int cb = i & 31;
    float4 v = out4[i];
    float4 s = sc4[cb];
    float4 t = sc4[32 + cb];
    v.x = v.x*s.x + t.x; v.y = v.y*s.y + t.y;
    v.z = v.z*s.z + t.z; v.w = v.w*s.w + t.w;
    out4[i] = v;
  }
}

extern "C" void kernel_launch(void* const* d_in, const int* in_sizes, int n_in,
                              void* d_out, int out_size, void* d_ws, size_t ws_size,
                              hipStream_t stream){
  const float* x     = (const float*)d_in[0];
  const int*   ei    = (const int*)d_in[1];      // int64 staged as int32 by harness
  const float* W     = (const float*)d_in[2];
  const float* b     = (const float*)d_in[3];
  const float* RW    = (const float*)d_in[4];
  const float* rb    = (const float*)d_in[5];
  const float* gamma = (const float*)d_in[6];
  const float* beta  = (const float*)d_in[7];
  float* out = (float*)d_out;
  unsigned* out_u = (unsigned*)d_out;
  const int N = in_sizes[0] / D;
  const int E = in_sizes[1] / 2;

  char* ws = (char*)d_ws;
  size_t o = 0;
  auto alloc = [&](size_t bytes)->void*{
    void* p = ws + o;
    o += (bytes + 255) & ~size_t(255);
    return p;
  };
  int*      cnt    = (int*)alloc((size_t)N*4);
  int*      off    = (int*)alloc((size_t)N*4);
  int*      cursor = (int*)alloc((size_t)N*4);
  int*      bsum   = (int*)alloc(512*4);
  float*    colsum = (float*)alloc(256*4);   // interleaved [sum,sumsq] per col
  float*    scale  = (float*)alloc(256*4);   // [0..127]=scale, [128..255]=shift
  unsigned* wsW    = (unsigned*)alloc(16384*4);  // swizzled bf16 Wt|RWt
  int*      elist  = (int*)alloc((size_t)E*4);
  // total ~3.8 MB

  hipMemsetAsync(cnt, 0, (size_t)N*4, stream);
  hipMemsetAsync(colsum, 0, 256*4, stream);

  int egrid = (E + 255)/256;
  int nb = (N + 255)/256;
  k_deg  <<<egrid, 256, 0, stream>>>(ei, cnt, E);
  k_scan1<<<nb,    256, 0, stream>>>(cnt, off, bsum, N);
  k_scan2<<<1,     512, 0, stream>>>(bsum, nb);
  k_scan3<<<nb,    256, 0, stream>>>(off, bsum, cursor, N);
  k_prep <<<(N*DW + 255)/256, 256, 0, stream>>>(x, cnt, out_u, N);
  k_wprep<<<64,    256, 0, stream>>>(W, RW, wsW);
  k_fill <<<egrid, 256, 0, stream>>>(ei, cursor, elist, E);
  k_agg  <<<4096,  256, 0, stream>>>(out_u, elist, off, cnt, N);
  k_gemm <<<(N + 127)/128, 512, 0, stream>>>(wsW, b, rb, cnt, out, colsum, N);
  k_bnfinal<<<1, 128, 0, stream>>>(colsum, gamma, beta, scale, (float)N);
  k_norm <<<2048, 256, 0, stream>>>((float4*)out, (const float4*)scale, N*32);
}

// Round 4
// 269.862 us; speedup vs baseline: 2.1870x; 1.1175x over previous
//
#include <hip/hip_runtime.h>
#include <math.h>

#define D 128
#define DW 64   // bf16-pair dwords per row (128 bf16 values)

typedef __attribute__((ext_vector_type(8))) short bf16x8;
typedef __attribute__((ext_vector_type(4))) float f32x4;
union U4 { uint4 u; bf16x8 f; };

__device__ __forceinline__ float blo(unsigned p){ return __uint_as_float(p << 16); }
__device__ __forceinline__ float bhi(unsigned p){ return __uint_as_float(p & 0xffff0000u); }
__device__ __forceinline__ unsigned bpack(float a, float b){
  unsigned x = __float_as_uint(a), y = __float_as_uint(b);
  x += 0x7fffu + ((x >> 16) & 1u);   // RNE
  y += 0x7fffu + ((y >> 16) & 1u);
  return (x >> 16) | (y & 0xffff0000u);
}

// d_out doubles as scratch: row i = 128 dwords.
//   dwords [i*128 ..  i*128+64)  : aggx row i (bf16 pairs)  -- written by k_agg
//   dwords [i*128+64 .. i*128+128): xb   row i (bf16 pairs)  -- written by k_prep
// k_gemm reads both for its rows, then overwrites the full row with final floats.

// ---- in-degree count (self-loop added later as +1) ----
__global__ void k_deg(const int* __restrict__ ei, int* __restrict__ cnt, int E){
  int e = blockIdx.x*256 + threadIdx.x;
  if (e < E) atomicAdd(cnt + ei[E + e], 1);
}

// ---- exclusive prefix sum over cnt[N]: 3 kernels ----
__global__ void k_scan1(const int* __restrict__ cnt, int* __restrict__ off,
                        int* __restrict__ bsum, int N){
  __shared__ int sm[256];
  int i = blockIdx.x*256 + threadIdx.x;
  int v = (i < N) ? cnt[i] : 0;
  int acc = v;
  sm[threadIdx.x] = acc;
  __syncthreads();
  for (int s = 1; s < 256; s <<= 1){
    int t = (threadIdx.x >= s) ? sm[threadIdx.x - s] : 0;
    __syncthreads();
    acc += t;
    sm[threadIdx.x] = acc;
    __syncthreads();
  }
  if (i < N) off[i] = acc - v;
  if (threadIdx.x == 255) bsum[blockIdx.x] = acc;
}

__global__ void k_scan2(int* __restrict__ bsum, int nb){
  __shared__ int sm[512];
  int v = (threadIdx.x < nb) ? bsum[threadIdx.x] : 0;
  int acc = v;
  sm[threadIdx.x] = acc;
  __syncthreads();
  for (int s = 1; s < 512; s <<= 1){
    int t = (threadIdx.x >= s) ? sm[threadIdx.x - s] : 0;
    __syncthreads();
    acc += t;
    sm[threadIdx.x] = acc;
    __syncthreads();
  }
  if (threadIdx.x < nb) bsum[threadIdx.x] = acc - v;
}

__global__ void k_scan3(int* __restrict__ off, const int* __restrict__ bsum,
                        int* __restrict__ cursor, int N){
  int i = blockIdx.x*256 + threadIdx.x;
  if (i < N){
    int o = off[i] + bsum[blockIdx.x];
    off[i] = o;
    cursor[i] = o;
  }
}

// ---- xb[i] = bf16(x[i] * dis[i]); store in out upper half (float4 loads) ----
__global__ void k_prep(const float* __restrict__ x, const int* __restrict__ cnt,
                       unsigned* __restrict__ out_u, int N){
  int idx = blockIdx.x*256 + threadIdx.x;   // N*32 total
  if (idx >= N*32) return;
  int row = idx >> 5, q = idx & 31;
  float dis = rsqrtf((float)(cnt[row] + 1));
  float4 xv = reinterpret_cast<const float4*>(x)[idx];
  uint2 r; r.x = bpack(xv.x*dis, xv.y*dis); r.y = bpack(xv.z*dis, xv.w*dis);
  reinterpret_cast<uint2*>(out_u)[(size_t)row*64 + 32 + q] = r;
}

// ---- W/RW -> bf16, transposed (Wt[c][k]) + XOR-swizzled, into ws ----
__global__ void k_wprep(const float* __restrict__ W, const float* __restrict__ RW,
                        unsigned* __restrict__ dst){
  int idx = blockIdx.x*256 + threadIdx.x;   // 16384 total
  int m = idx >> 13;
  int w = idx & 8191;
  int c = w >> 6, kd = w & 63;
  const float* src = m ? RW : W;
  float a = src[(2*kd)*128 + c];
  float b = src[(2*kd+1)*128 + c];
  dst[(m<<13) + c*64 + (kd ^ ((c & 7) << 2))] = bpack(a, b);
}

// ---- scatter edge src ids into CSR buckets (keyed by dst) ----
__global__ void k_fill(const int* __restrict__ ei, int* __restrict__ cursor,
                       int* __restrict__ elist, int E){
  int e = blockIdx.x*256 + threadIdx.x;
  if (e < E){
    int d = ei[E + e];
    int pos = atomicAdd(cursor + d, 1);
    elist[pos] = ei[e];
  }
}

// ---- one wave per node, 4 gathers in flight ----
__global__ __launch_bounds__(256) void k_agg(unsigned* __restrict__ out_u,
    const int* __restrict__ elist, const int* __restrict__ off,
    const int* __restrict__ cnt, int N){
  const int lane = threadIdx.x & 63;
  int wid = blockIdx.x*4 + (threadIdx.x >> 6);
  const int nw = gridDim.x*4;
  for (int i = wid; i < N; i += nw){
    int node = __builtin_amdgcn_readfirstlane(i);
    int o = off[node];
    int c = cnt[node];
    unsigned ps = out_u[(size_t)node*128 + 64 + lane];   // self-loop, issued early
    float a0 = 0.f, a1 = 0.f;
    for (int j0 = 0; j0 < c; j0 += 64){
      int m = c - j0; if (m > 64) m = 64;
      int li = lane < m ? lane : m-1;
      int sid = elist[o + j0 + li];
      for (int jj = 0; jj < m; jj += 4){
        int s0 = __shfl(sid, jj);
        int s1 = __shfl(sid, jj+1 < m ? jj+1 : m-1);
        int s2 = __shfl(sid, jj+2 < m ? jj+2 : m-1);
        int s3 = __shfl(sid, jj+3 < m ? jj+3 : m-1);
        unsigned p0 = out_u[(size_t)s0*128 + 64 + lane];
        unsigned p1 = out_u[(size_t)s1*128 + 64 + lane];
        unsigned p2 = out_u[(size_t)s2*128 + 64 + lane];
        unsigned p3 = out_u[(size_t)s3*128 + 64 + lane];
        if (jj+1 >= m) p1 = 0;        // wave-uniform masks (m uniform)
        if (jj+2 >= m) p2 = 0;
        if (jj+3 >= m) p3 = 0;
        a0 += blo(p0) + blo(p1) + blo(p2) + blo(p3);
        a1 += bhi(p0) + bhi(p1) + bhi(p2) + bhi(p3);
      }
    }
    a0 += blo(ps); a1 += bhi(ps);
    float dis = rsqrtf((float)(c + 1));
    out_u[(size_t)node*128 + lane] = bpack(a0*dis, a1*dis);
  }
}

// ---- MFMA GEMM: out = aggx@W + b + relu((xb@RW)*s + rb); BN partial sums ----
__global__ __launch_bounds__(512) void k_gemm(
    const unsigned* __restrict__ wsW,     // 16384 dwords: swizzled Wt | RWt
    const float* __restrict__ bias, const float* __restrict__ rbias,
    const int* __restrict__ cnt,
    float* __restrict__ out, float* __restrict__ colsum, int N)
{
  __shared__ unsigned lds[16384];   // 64KB: [0..8191]=Wt, [8192..]=RWt (swizzled)
  unsigned* out_u = reinterpret_cast<unsigned*>(out);
  for (int i = threadIdx.x; i < 16384; i += 512) lds[i] = wsW[i];
  __syncthreads();

  const int lane = threadIdx.x & 63;
  const int wave = threadIdx.x >> 6;
  const int lo = lane & 15, hi = lane >> 4;
  const int rowbase = (blockIdx.x * 8 + wave) * 16;

  float bcol[8], rbcol[8];
  #pragma unroll
  for (int ct = 0; ct < 8; ++ct){
    bcol[ct]  = bias[ct*16 + lo];
    rbcol[ct] = rbias[ct*16 + lo];
  }

  int arow = rowbase + lo; if (arow >= N) arow = N - 1;   // clamped rows discarded
  U4 aggF[4], xbF[4];
  #pragma unroll
  for (int kk = 0; kk < 4; ++kk){
    aggF[kk].u = *(const uint4*)&out_u[(size_t)arow*128 + kk*16 + hi*4];
    xbF[kk].u  = *(const uint4*)&out_u[(size_t)arow*128 + 64 + kk*16 + hi*4];
  }

  f32x4 accA[8], accR[8];
  #pragma unroll
  for (int ct = 0; ct < 8; ++ct){
    accA[ct] = (f32x4){0.f,0.f,0.f,0.f};
    accR[ct] = (f32x4){0.f,0.f,0.f,0.f};
  }

  #pragma unroll
  for (int ct = 0; ct < 8; ++ct){
    const int c = ct*16 + lo;
    #pragma unroll
    for (int kk = 0; kk < 4; ++kk){
      int kd = (kk*16 + hi*4) ^ ((c & 7) << 2);
      U4 wf, rf;
      wf.u = *(const uint4*)&lds[c*64 + kd];
      rf.u = *(const uint4*)&lds[8192 + c*64 + kd];
      accA[ct] = __builtin_amdgcn_mfma_f32_16x16x32_bf16(aggF[kk].f, wf.f, accA[ct], 0,0,0);
      accR[ct] = __builtin_amdgcn_mfma_f32_16x16x32_bf16(xbF[kk].f, rf.f, accR[ct], 0,0,0);
    }
  }

  // epilogue: C/D layout col=lane&15, row=hi*4+reg
  float s_[4];
  #pragma unroll
  for (int j = 0; j < 4; ++j){
    int r = rowbase + hi*4 + j;
    int rc = r < N ? r : N - 1;
    s_[j] = sqrtf((float)(cnt[rc] + 1));   // undo dis scaling on residual
  }
  float cs[8], cq[8];
  #pragma unroll
  for (int ct = 0; ct < 8; ++ct){ cs[ct] = 0.f; cq[ct] = 0.f; }

  #pragma unroll
  for (int ct = 0; ct < 8; ++ct){
    const int col = ct*16 + lo;
    #pragma unroll
    for (int j = 0; j < 4; ++j){
      int r = rowbase + hi*4 + j;
      if (r < N){
        float y = accA[ct][j] + bcol[ct] + fmaxf(accR[ct][j]*s_[j] + rbcol[ct], 0.f);
        out[(size_t)r*128 + col] = y;
        cs[ct] += y; cq[ct] += y*y;
      }
    }
  }

  #pragma unroll
  for (int ct = 0; ct < 8; ++ct){
    cs[ct] += __shfl_xor(cs[ct], 16); cs[ct] += __shfl_xor(cs[ct], 32);
    cq[ct] += __shfl_xor(cq[ct], 16); cq[ct] += __shfl_xor(cq[ct], 32);
  }
  __syncthreads();                 // Wt no longer needed; reuse LDS
  float* red = reinterpret_cast<float*>(lds);
  if (lane < 16){
    #pragma unroll
    for (int ct = 0; ct < 8; ++ct){
      int col = ct*16 + lane;
      red[wave*256 + 2*col]     = cs[ct];
      red[wave*256 + 2*col + 1] = cq[ct];
    }
  }
  __syncthreads();
  if (threadIdx.x < 256){
    float t = 0.f;
    #pragma unroll
    for (int w = 0; w < 8; ++w) t += red[w*256 + threadIdx.x];
    atomicAdd(colsum + threadIdx.x, t);
  }
}

// ---- BN finalize (per-block, redundant) + in-place normalize ----
__global__ void k_norm(float4* __restrict__ out4, const float* __restrict__ colsum,
                       const float* __restrict__ gamma, const float* __restrict__ beta,
                       float fN, int n4){
  __shared__ float sc[256];
  if (threadIdx.x < 128){
    int c = threadIdx.x;
    float mean = colsum[2*c] / fN;
    float var  = fmaxf(colsum[2*c + 1] / fN - mean*mean, 0.f);
    float s = gamma[c] * rsqrtf(var + 1e-5f);
    sc[c] = s;
    sc[128 + c] = beta[c] - mean * s;
  }
  __syncthreads();
  const float4* s4 = reinterpret_cast<const float4*>(sc);
  int idx = blockIdx.x*256 + threadIdx.x;
  int stride = gridDim.x*256;
  for (int i = idx; i < n4; i += stride){
    int cb = i & 31;
    float4 v = out4[i];
    float4 s = s4[cb];
    float4 t = s4[32 + cb];
    v.x = v.x*s.x + t.x; v.y = v.y*s.y + t.y;
    v.z = v.z*s.z + t.z; v.w = v.w*s.w + t.w;
    out4[i] = v;
  }
}

extern "C" void kernel_launch(void* const* d_in, const int* in_sizes, int n_in,
                              void* d_out, int out_size, void* d_ws, size_t ws_size,
                              hipStream_t stream){
  const float* x     = (const float*)d_in[0];
  const int*   ei    = (const int*)d_in[1];      // int64 staged as int32 by harness
  const float* W     = (const float*)d_in[2];
  const float* b     = (const float*)d_in[3];
  const float* RW    = (const float*)d_in[4];
  const float* rb    = (const float*)d_in[5];
  const float* gamma = (const float*)d_in[6];
  const float* beta  = (const float*)d_in[7];
  float* out = (float*)d_out;
  unsigned* out_u = (unsigned*)d_out;
  const int N = in_sizes[0] / D;
  const int E = in_sizes[1] / 2;

  char* ws = (char*)d_ws;
  size_t o = 0;
  auto alloc = [&](size_t bytes)->void*{
    void* p = ws + o;
    o += (bytes + 255) & ~size_t(255);
    return p;
  };
  int*      cnt    = (int*)alloc((size_t)N*4);
  int*      off    = (int*)alloc((size_t)N*4);
  int*      cursor = (int*)alloc((size_t)N*4);
  int*      bsum   = (int*)alloc(512*4);
  float*    colsum = (float*)alloc(256*4);       // interleaved [sum,sumsq] per col
  unsigned* wsW    = (unsigned*)alloc(16384*4);  // swizzled bf16 Wt|RWt
  int*      elist  = (int*)alloc((size_t)E*4);
  // total ~3.8 MB

  hipMemsetAsync(cnt, 0, (size_t)N*4, stream);
  hipMemsetAsync(colsum, 0, 256*4, stream);

  int egrid = (E + 255)/256;
  int nb = (N + 255)/256;
  k_deg  <<<egrid, 256, 0, stream>>>(ei, cnt, E);
  k_scan1<<<nb,    256, 0, stream>>>(cnt, off, bsum, N);
  k_scan2<<<1,     512, 0, stream>>>(bsum, nb);
  k_scan3<<<nb,    256, 0, stream>>>(off, bsum, cursor, N);
  k_prep <<<(N*32 + 255)/256, 256, 0, stream>>>(x, cnt, out_u, N);
  k_wprep<<<64,    256, 0, stream>>>(W, RW, wsW);
  k_fill <<<egrid, 256, 0, stream>>>(ei, cursor, elist, E);
  k_agg  <<<4096,  256, 0, stream>>>(out_u, elist, off, cnt, N);
  k_gemm <<<(N + 127)/128, 512, 0, stream>>>(wsW, b, rb, cnt, out, colsum, N);
  k_norm <<<2048,  256, 0, stream>>>((float4*)out, colsum, gamma, beta, (float)N, N*32);
}